// Round 2
// baseline (580.226 us; speedup 1.0000x reference)
//
#include <hip/hip_runtime.h>
#include <hip/hip_bf16.h>
#include <stdint.h>

typedef unsigned short bf16_t;
typedef __attribute__((ext_vector_type(8))) short short8;
typedef __attribute__((ext_vector_type(4))) float f32x4;

#define BM 128
#define BN 128
#define BK 32

__device__ __forceinline__ bf16_t f2b(float f) {
    union { float f; uint32_t u; } v; v.f = f;
    uint32_t u = v.u;
    return (bf16_t)((u + 0x7FFFu + ((u >> 16) & 1u)) >> 16);
}

__global__ __launch_bounds__(256) void cvt_f32_bf16(const float* __restrict__ in,
                                                    bf16_t* __restrict__ out, int n4) {
    int i = blockIdx.x * blockDim.x + threadIdx.x;
    if (i >= n4) return;
    float4 f = ((const float4*)in)[i];
    ushort4 o;
    o.x = f2b(f.x); o.y = f2b(f.y); o.z = f2b(f.z); o.w = f2b(f.w);
    ((ushort4*)out)[i] = o;
}

__device__ __forceinline__ void lds_dma16(const void* g, void* l) {
    __builtin_amdgcn_global_load_lds(
        (const __attribute__((address_space(1))) void*)g,
        (__attribute__((address_space(3))) void*)l, 16, 0, 0);
}

// C = A (M x K row-major, lda) * B^T (B stored N x K row-major, ldb) + epilogue
// MODE 0: out bf16 row-major, val=(acc+bias[col])*scale          (Q/K proj)
// MODE 2: out bf16 transposed Vt[b][col][s], val=acc+bias[col]   (V proj)
template <int MODE>
__global__ __launch_bounds__(256)
void gemm_bt(const bf16_t* __restrict__ Ag, int lda,
             const bf16_t* __restrict__ Bg, int ldb,
             const float* __restrict__ bias,
             void* __restrict__ outp, int ldo,
             int K, float scale)
{
    __shared__ bf16_t lsA[BM * BK];
    __shared__ bf16_t lsB[BN * BK];

    const int tid  = threadIdx.x;
    const int lane = tid & 63;
    const int w    = tid >> 6;
    const int wm   = w & 1, wn = w >> 1;
    const int ll   = lane & 15;
    const int quad = lane >> 4;

    const int m0 = blockIdx.y * BM;
    const int n0 = blockIdx.x * BN;

    const bf16_t* A = Ag;
    const bf16_t* B = Bg;

    f32x4 acc[4][4];
#pragma unroll
    for (int i = 0; i < 4; i++)
#pragma unroll
        for (int j = 0; j < 4; j++) acc[i][j] = (f32x4){0.f, 0.f, 0.f, 0.f};

    for (int k0 = 0; k0 < K; k0 += BK) {
#pragma unroll
        for (int c = 0; c < 2; ++c) {
            const int base = (c * 4 + w) * 64;
            const int idx  = base + lane;
            const int row  = idx >> 2;
            const int kc   = (idx & 3) << 3;
            lds_dma16(A + (size_t)(m0 + row) * lda + k0 + kc, (char*)lsA + base * 16);
            lds_dma16(B + (size_t)(n0 + row) * ldb + k0 + kc, (char*)lsB + base * 16);
        }
        __syncthreads();

        short8 af[4], bf[4];
#pragma unroll
        for (int i = 0; i < 4; i++) {
            af[i] = *(const short8*)(lsA + (wm * 64 + i * 16 + ll) * BK + quad * 8);
            bf[i] = *(const short8*)(lsB + (wn * 64 + i * 16 + ll) * BK + quad * 8);
        }
#pragma unroll
        for (int i = 0; i < 4; i++)
#pragma unroll
            for (int j = 0; j < 4; j++)
                acc[i][j] = __builtin_amdgcn_mfma_f32_16x16x32_bf16(af[i], bf[j], acc[i][j], 0, 0, 0);
        __syncthreads();
    }

#pragma unroll
    for (int i = 0; i < 4; i++) {
#pragma unroll
        for (int j = 0; j < 4; j++) {
            const int col  = n0 + wn * 64 + j * 16 + ll;
            const int rowb = m0 + wm * 64 + i * 16 + quad * 4;
            f32x4 a = acc[i][j];
            if (MODE == 0) {
                const float bv = bias[col];
                bf16_t* o = (bf16_t*)outp;
#pragma unroll
                for (int r = 0; r < 4; r++)
                    o[(size_t)(rowb + r) * ldo + col] = f2b((a[r] + bv) * scale);
            } else { // MODE 2: Vt[b][col][s]
                const float bv = bias[col];
                bf16_t* o = (bf16_t*)outp;
                const int b = rowb >> 12;
                const int s = rowb & 4095;
                ushort4 pk;
                pk.x = f2b(a[0] + bv);
                pk.y = f2b(a[1] + bv);
                pk.z = f2b(a[2] + bv);
                pk.w = f2b(a[3] + bv);
                *(ushort4*)(o + ((size_t)b * 512 + col) * 4096 + s) = pk;
            }
        }
    }
}

// ---------------- fused sigmoid attention ----------------
// grid (128, 4): x = q-tile of 32 rows, y = batch. 256 threads, 4 waves.
// Q: [z][4096][512] bf16 (pre-scaled 1/sqrt(D)), K same, Vt: [z][512][4096] bf16.
// out: fp32 [z][4096][512].
__global__ __launch_bounds__(256, 2)
void attn_fused(const bf16_t* __restrict__ Qg, const bf16_t* __restrict__ Kg,
                const bf16_t* __restrict__ Vtg, const float* __restrict__ biasf,
                float* __restrict__ outg)
{
    __shared__ __align__(16) bf16_t lsQ[16384];   // [dchunk=16][row=32][32 d]  32 KB
    __shared__ __align__(16) bf16_t lsS[16384];   // K: [t=4][row=128][32 d] / V: [d=512][32 s]
    __shared__ __align__(16) bf16_t lsP[32 * 136]; // P tile row-major, padded ld=136

    const int tid  = threadIdx.x;
    const int lane = tid & 63;
    const int w    = tid >> 6;
    const int ll   = lane & 15;
    const int quad = lane >> 4;

    const int q0 = blockIdx.x * 32;
    const int z  = blockIdx.y;

    const bf16_t* Qz = Qg + (size_t)z * 4096 * 512;
    const bf16_t* Kz = Kg + (size_t)z * 4096 * 512;
    const bf16_t* Vz = Vtg + (size_t)z * 512 * 4096;

    // ---- stage Q once: layout [dchunk16][row32][32d]; slot*16B == lds offset ----
#pragma unroll
    for (int c = 0; c < 8; c++) {
        const int slot = c * 256 + tid;
        const int goff = (q0 + ((slot >> 2) & 31)) * 512 + (slot >> 7) * 32 + (slot & 3) * 8;
        lds_dma16(Qz + goff, (char*)lsQ + (c * 256 + w * 64) * 16);
    }

    // per-thread staging offsets (element units), invariant across tiles
    int koff[8], voff[8];
#pragma unroll
    for (int c = 0; c < 8; c++) {
        const int slot = c * 256 + tid;
        koff[c] = ((slot >> 2) & 127) * 512 + (slot >> 9) * 32 + (slot & 3) * 8;
        voff[c] = (slot >> 2) * 4096 + (slot & 3) * 8;
    }

    f32x4 accO[2][8];
#pragma unroll
    for (int i = 0; i < 2; i++)
#pragma unroll
        for (int j = 0; j < 8; j++) accO[i][j] = (f32x4){0.f, 0.f, 0.f, 0.f};

    for (int n0 = 0; n0 < 4096; n0 += 128) {
        // ---- S = Q K^T over d-chunks of 128 ----
        f32x4 accS[2][2];
#pragma unroll
        for (int i = 0; i < 2; i++)
#pragma unroll
            for (int j = 0; j < 2; j++) accS[i][j] = (f32x4){0.f, 0.f, 0.f, 0.f};

        for (int dc = 0; dc < 4; dc++) {
            __syncthreads();  // staging buffer free
            const bf16_t* Kb_ = Kz + (size_t)n0 * 512 + dc * 128;
#pragma unroll
            for (int c = 0; c < 8; c++)
                lds_dma16(Kb_ + koff[c], (char*)lsS + (c * 256 + w * 64) * 16);
            __syncthreads();  // staging visible
#pragma unroll
            for (int t = 0; t < 4; t++) {
                short8 aQ0 = *(const short8*)(lsQ + (dc * 4 + t) * 1024 + ll * 32 + quad * 8);
                short8 aQ1 = *(const short8*)(lsQ + (dc * 4 + t) * 1024 + (16 + ll) * 32 + quad * 8);
                short8 bK0 = *(const short8*)(lsS + (t * 128 + w * 32 + ll) * 32 + quad * 8);
                short8 bK1 = *(const short8*)(lsS + (t * 128 + w * 32 + 16 + ll) * 32 + quad * 8);
                accS[0][0] = __builtin_amdgcn_mfma_f32_16x16x32_bf16(aQ0, bK0, accS[0][0], 0, 0, 0);
                accS[0][1] = __builtin_amdgcn_mfma_f32_16x16x32_bf16(aQ0, bK1, accS[0][1], 0, 0, 0);
                accS[1][0] = __builtin_amdgcn_mfma_f32_16x16x32_bf16(aQ1, bK0, accS[1][0], 0, 0, 0);
                accS[1][1] = __builtin_amdgcn_mfma_f32_16x16x32_bf16(aQ1, bK1, accS[1][1], 0, 0, 0);
            }
        }

        // ---- sigmoid(S + bias) -> P (bf16, LDS) ----
#pragma unroll
        for (int mi = 0; mi < 2; mi++) {
#pragma unroll
            for (int nj = 0; nj < 2; nj++) {
                const int colL = w * 32 + nj * 16 + ll;
#pragma unroll
                for (int r = 0; r < 4; r++) {
                    const int row = mi * 16 + quad * 4 + r;
                    const float v = accS[mi][nj][r] +
                                    biasf[(size_t)(q0 + row) * 4096 + n0 + colL];
                    const float p = __builtin_amdgcn_rcpf(1.f + __expf(-v));
                    lsP[row * 136 + colL] = f2b(p);
                }
            }
        }

        // ---- O += P * V over s-chunks of 32 ----
#pragma unroll
        for (int t = 0; t < 4; t++) {
            __syncthreads();  // K/V staging reads done; t==0 also orders lsP writes
            const bf16_t* Vb_ = Vz + n0 + t * 32;
#pragma unroll
            for (int c = 0; c < 8; c++)
                lds_dma16(Vb_ + voff[c], (char*)lsS + (c * 256 + w * 64) * 16);
            __syncthreads();
            short8 aP0 = *(const short8*)(lsP + ll * 136 + t * 32 + quad * 8);
            short8 aP1 = *(const short8*)(lsP + (16 + ll) * 136 + t * 32 + quad * 8);
#pragma unroll
            for (int nj = 0; nj < 8; nj++) {
                short8 bV = *(const short8*)(lsS + (w * 128 + nj * 16 + ll) * 32 + quad * 8);
                accO[0][nj] = __builtin_amdgcn_mfma_f32_16x16x32_bf16(aP0, bV, accO[0][nj], 0, 0, 0);
                accO[1][nj] = __builtin_amdgcn_mfma_f32_16x16x32_bf16(aP1, bV, accO[1][nj], 0, 0, 0);
            }
        }
    }

    // ---- epilogue: out[z][q0+row][w*128 + nj*16 + ll] ----
#pragma unroll
    for (int mi = 0; mi < 2; mi++) {
#pragma unroll
        for (int nj = 0; nj < 8; nj++) {
            const int col = w * 128 + nj * 16 + ll;
#pragma unroll
            for (int r = 0; r < 4; r++) {
                const int row = q0 + mi * 16 + quad * 4 + r;
                outg[((size_t)z * 4096 + row) * 512 + col] = accO[mi][nj][r];
            }
        }
    }
}

extern "C" void kernel_launch(void* const* d_in, const int* in_sizes, int n_in,
                              void* d_out, int out_size, void* d_ws, size_t ws_size,
                              hipStream_t stream) {
    (void)in_sizes; (void)n_in; (void)out_size; (void)ws_size;
    const float* x    = (const float*)d_in[0];
    const float* bias = (const float*)d_in[1];
    const float* Wq_w = (const float*)d_in[2];
    const float* Wq_b = (const float*)d_in[3];
    const float* Wk_w = (const float*)d_in[4];
    const float* Wk_b = (const float*)d_in[5];
    const float* Wv_w = (const float*)d_in[6];
    const float* Wv_b = (const float*)d_in[7];
    float* out = (float*)d_out;

    // workspace layout (bf16 elements)
    bf16_t* Xb = (bf16_t*)d_ws;                    // 16384 x 512
    bf16_t* Wb = Xb + (size_t)16384 * 512;         // 3 x 512 x 512
    bf16_t* Qb = Wb + (size_t)3 * 512 * 512;       // 16384 x 512 (pre-scaled by 1/sqrt(D))
    bf16_t* Kb = Qb + (size_t)16384 * 512;         // 16384 x 512
    bf16_t* Vt = Kb + (size_t)16384 * 512;         // 4 x 512 x 4096 (transposed V)

    cvt_f32_bf16<<<8192, 256, 0, stream>>>(x, Xb, 2097152);
    cvt_f32_bf16<<<256, 256, 0, stream>>>(Wq_w, Wb, 65536);
    cvt_f32_bf16<<<256, 256, 0, stream>>>(Wk_w, Wb + 262144, 65536);
    cvt_f32_bf16<<<256, 256, 0, stream>>>(Wv_w, Wb + 524288, 65536);

    const float inv = 0.044194173824159216f;  // 1/sqrt(512)

    // projections: M=16384, N=512, K=512
    gemm_bt<0><<<dim3(4, 128), 256, 0, stream>>>(Xb, 512, Wb, 512,
                                                 Wq_b, Qb, 512, 512, inv);
    gemm_bt<0><<<dim3(4, 128), 256, 0, stream>>>(Xb, 512, Wb + 262144, 512,
                                                 Wk_b, Kb, 512, 512, 1.0f);
    gemm_bt<2><<<dim3(4, 128), 256, 0, stream>>>(Xb, 512, Wb + 524288, 512,
                                                 Wv_b, Vt, 0, 512, 1.0f);

    // fused sigmoid attention: scores + sigmoid + PV in one pass
    attn_fused<<<dim3(128, 4), 256, 0, stream>>>(Qb, Kb, Vt, bias, out);
}